// Round 22
// baseline (129.134 us; speedup 1.0000x reference)
//
#include <hip/hip_runtime.h>
#include <hip/hip_bf16.h>
#include <math.h>

#define V_ 50000
#define E_ 256
#define H_ 256
#define B_ 64
#define S_ 2048
#define NCHK 32            // S/64 strips == score chunks

typedef __attribute__((ext_vector_type(4))) float f32x4;
typedef __attribute__((ext_vector_type(16))) float f32x16;
typedef __attribute__((ext_vector_type(8))) __bf16 bf16x8;

static __device__ __forceinline__ f32x4 mfma16(bf16x8 a, bf16x8 b, f32x4 c) {
  return __builtin_amdgcn_mfma_f32_16x16x32_bf16(a, b, c, 0, 0, 0);
}
static __device__ __forceinline__ f32x16 mfma32(bf16x8 a, bf16x8 b, f32x16 c) {
  return __builtin_amdgcn_mfma_f32_32x32x16_bf16(a, b, c, 0, 0, 0);
}
static __device__ __forceinline__ float fast_tanh(float x) {
  const float e2 = __expf(2.0f * x);
  return 1.0f - 2.0f / (e2 + 1.0f);
}
// async global->LDS, 16B per lane; dst is wave-uniform base (HW adds lane*16)
static __device__ __forceinline__ void gll16(const float* g, void* l) {
  __builtin_amdgcn_global_load_lds(
      (const __attribute__((address_space(1))) void*)g,
      (__attribute__((address_space(3))) void*)l, 16, 0, 0);
}
#define WAITC(n) asm volatile("s_waitcnt vmcnt(%0)" :: "n"(n) : "memory")

// ---------------- prep: xU = x@U ; xWih = x@W_ih^T + b_ih + b_hh ----------------
__global__ __launch_bounds__(256) void prep_k(
    const int* __restrict__ inp, const float* __restrict__ emb,
    const float* __restrict__ U, const float* __restrict__ W_ih,
    const float* __restrict__ b_ih, const float* __restrict__ b_hh,
    float* __restrict__ xU, float* __restrict__ xWih) {
  const int b = blockIdx.x, h = threadIdx.x;
  __shared__ float xs[H_];
  xs[h] = emb[(size_t)inp[b] * E_ + h];
  __syncthreads();
  float au = 0.f, aw = 0.f;
  const float* __restrict__ wir = W_ih + (size_t)h * E_;
  for (int k = 0; k < H_; k += 4) {
    const float4 x4 = *reinterpret_cast<const float4*>(&xs[k]);
    const float4 w4 = *reinterpret_cast<const float4*>(wir + k);
    aw = fmaf(x4.x, w4.x, aw); aw = fmaf(x4.y, w4.y, aw);
    aw = fmaf(x4.z, w4.z, aw); aw = fmaf(x4.w, w4.w, aw);
    au = fmaf(x4.x, U[(size_t)(k + 0) * H_ + h], au);
    au = fmaf(x4.y, U[(size_t)(k + 1) * H_ + h], au);
    au = fmaf(x4.z, U[(size_t)(k + 2) * H_ + h], au);
    au = fmaf(x4.w, U[(size_t)(k + 3) * H_ + h], au);
  }
  xU[b * H_ + h] = au;
  xWih[b * H_ + h] = aw + b_ih[h] + b_hh[h];
}

// ---------------- prep W: bf16 table wt2[k>>3][col][k&7] (koct-major) ----------------
__global__ __launch_bounds__(256) void prep_w(
    const float* __restrict__ W, __bf16* __restrict__ wt2) {
  const int idx = blockIdx.x * 256 + threadIdx.x;
  const int k = idx >> 8, col = idx & 255;
  wt2[((size_t)(k >> 3) * 256 + col) * 8 + (k & 7)] = (__bf16)W[(size_t)k * H_ + col];
}

// ---------------- fused attention: PERSISTENT blocks, rolling slab pipeline ----------------
// 512 blocks (2/CU, one cohort). Block bx: batch b = bx>>3, strips u0..u0+3
// where u0 = (bx&7)*4. 4 units x 16 slabs = 64 global slabs g, slot = g&7,
// stage-ahead 6 -> unit u+1's slabs are staged during unit u's last iters
// (pipeline never drains between units). Counted vmcnt (exact tables), one
// barrier per slab. Epilogue ends with vmcnt(0) drain (resets counts).
// Wave = 64 rows x 64 cols (4 col-group waves, no B duplication).
// 1-term bf16 (absmax 0.25 verified). ctx re-reads enc from global (R18).
__global__ __launch_bounds__(256, 3) void attn_fused(
    const float* __restrict__ enc, const __bf16* __restrict__ wt2,
    const float* __restrict__ xU, const float* __restrict__ vv,
    float* __restrict__ ctxp, float* __restrict__ mlout) {
  const int t = threadIdx.x;
  const int w = t >> 6, l = t & 63, l31 = l & 31, h5 = l >> 5;

  __shared__ __align__(16) char Aring[8 * 4096];   // 32 KB rolling ring
  __shared__ float ered[4][64];
  __shared__ float wgt[64];
  __shared__ float mlS[2];

  const int bx = blockIdx.x;
  const int b = bx >> 3;
  const int u0 = (bx & 7) * 4;     // first strip index

  // epilogue constants (before the drain so counts stay exact)
  float xu[2], vw[2];
#pragma unroll
  for (int cf = 0; cf < 2; ++cf) {
    const int col = w * 64 + cf * 32 + l31;
    xu[cf] = xU[b * H_ + col];
    vw[cf] = vv[col];
  }
  __builtin_amdgcn_sched_barrier(0);
  asm volatile("s_waitcnt vmcnt(0)" ::: "memory");

  // staging map: lane i covers row i/4, chunk i&3; kchunk = pch ^ ((row>>1)&3)
  const int srow = t >> 2;
  const int pch = t & 3;
  const int kch = pch ^ ((srow >> 1) & 3);
  const float* __restrict__ base = enc + ((size_t)b * S_ + srow) * H_ + kch * 4;

#define STAGEG(slot_, addr_)                                    \
  gll16((addr_), Aring + (slot_) * 4096 + w * 1024);            \
  __builtin_amdgcn_sched_barrier(0);

  // prologue: slabs g=0..5 (unit 0) + B for slab 0
#pragma unroll
  for (int g = 0; g < 6; ++g) {
    STAGEG(g & 7, base + (size_t)u0 * 16384 + g * 16);
  }
  bf16x8 bh[2][2];
#pragma unroll
  for (int cf = 0; cf < 2; ++cf) {
    const int col = w * 64 + cf * 32 + l31;
    bh[0][cf] = *reinterpret_cast<const bf16x8*>(wt2 + ((size_t)h5 * 256 + col) * 8);
  }
  __builtin_amdgcn_sched_barrier(0);

  const int sxor = (l31 >> 1) & 3;

#pragma unroll 1
  for (int u = 0; u < 4; ++u) {
    const int ridxu = u0 + u;

    f32x16 acc[2][2];
#pragma unroll
    for (int rf = 0; rf < 2; ++rf)
#pragma unroll
      for (int cf = 0; cf < 2; ++cf) acc[rf][cf] = (f32x16)(0.f);

#pragma unroll
    for (int ks = 0; ks < 16; ++ks) {
      // ---- counted wait for slab (u,ks); N tables derived op-by-op ----
      if (u == 0) {
        if      (ks == 0) WAITC(7);
        else if (ks == 1) WAITC(9);
        else if (ks == 2) WAITC(11);
        else if (ks == 3) WAITC(13);
        else if (ks == 4) WAITC(15);
        else              WAITC(17);
      } else if (u == 3) {
        if      (ks == 0) WAITC(0);
        else if (ks == 1) WAITC(3);
        else if (ks == 2) WAITC(6);
        else if (ks == 3) WAITC(9);
        else if (ks == 4) WAITC(12);
        else if (ks == 5) WAITC(15);
        else if (ks <= 10) WAITC(17);
        else if (ks == 11) WAITC(16);
        else if (ks == 12) WAITC(15);
        else if (ks == 13) WAITC(14);
        else if (ks == 14) WAITC(13);
        else               WAITC(12);
      } else {
        if      (ks == 0) WAITC(0);
        else if (ks == 1) WAITC(3);
        else if (ks == 2) WAITC(6);
        else if (ks == 3) WAITC(9);
        else if (ks == 4) WAITC(12);
        else if (ks == 5) WAITC(15);
        else              WAITC(17);
      }
      __builtin_amdgcn_s_barrier();
      __builtin_amdgcn_sched_barrier(0);

      // ---- stage slab g+6 (skip past global slab 63) ----
      if (!(u == 3 && ks >= 10)) {
        const int gslot = (ks + 6) & 7;          // (16u+ks+6)&7, 16u%8==0
        const int ridx_g = ridxu + ((ks + 6) >> 4);
        STAGEG(gslot, base + (size_t)ridx_g * 16384 + ((ks + 6) & 15) * 16);
      }
      // ---- B prefetch for slab ks+1 (wraps to next unit's ks0; W identical) ----
      const int pb = ks & 1;
      if (!(u == 3 && ks == 15)) {
        const int ks2 = (ks + 1) & 15;
#pragma unroll
        for (int cf = 0; cf < 2; ++cf) {
          const int col = w * 64 + cf * 32 + l31;
          bh[pb ^ 1][cf] = *reinterpret_cast<const bf16x8*>(
              wt2 + ((size_t)(2 * ks2 + h5) * 256 + col) * 8);
        }
      }
      __builtin_amdgcn_sched_barrier(0);

      // ---- compute slab ks: 2 row-frags, single bf16 convert, 4 mfma32 ----
      bf16x8 ab[2];
#pragma unroll
      for (int rf = 0; rf < 2; ++rf) {
        const char* sb = Aring + (ks & 7) * 4096 + (rf * 32 + l31) * 64;
        const f32x4 c0 = *reinterpret_cast<const f32x4*>(sb + (((2 * h5 + 0) ^ sxor) << 4));
        const f32x4 c1 = *reinterpret_cast<const f32x4*>(sb + (((2 * h5 + 1) ^ sxor) << 4));
        const float xa[8] = {c0[0], c0[1], c0[2], c0[3], c1[0], c1[1], c1[2], c1[3]};
#pragma unroll
        for (int j = 0; j < 8; ++j) ab[rf][j] = (__bf16)xa[j];
      }
#pragma unroll
      for (int rf = 0; rf < 2; ++rf)
#pragma unroll
        for (int cf = 0; cf < 2; ++cf)
          acc[rf][cf] = mfma32(ab[rf], bh[pb][cf], acc[rf][cf]);
    }

    // ---- epilogue for unit u ----
    float rs[2][16];
#pragma unroll
    for (int rf = 0; rf < 2; ++rf)
#pragma unroll
      for (int reg = 0; reg < 16; ++reg) {
        float s = 0.f;
#pragma unroll
        for (int cf = 0; cf < 2; ++cf)
          s += fast_tanh(xu[cf] + acc[rf][cf][reg]) * vw[cf];
        rs[rf][reg] = s;
      }
#pragma unroll
    for (int o = 1; o < 32; o <<= 1)
#pragma unroll
      for (int rf = 0; rf < 2; ++rf)
#pragma unroll
        for (int reg = 0; reg < 16; ++reg)
          rs[rf][reg] += __shfl_xor(rs[rf][reg], o);
    if (l31 == 0) {
#pragma unroll
      for (int rf = 0; rf < 2; ++rf)
#pragma unroll
        for (int reg = 0; reg < 16; ++reg)
          ered[w][rf * 32 + (reg & 3) + 8 * (reg >> 2) + 4 * h5] = rs[rf][reg];
    }
    __syncthreads();

    if (t < 64) {
      const float es = ered[0][t] + ered[1][t] + ered[2][t] + ered[3][t];
      float m = es;
#pragma unroll
      for (int o = 1; o < 64; o <<= 1) m = fmaxf(m, __shfl_xor(m, o));
      const float we = __expf(es - m);
      float ls = we;
#pragma unroll
      for (int o = 1; o < 64; o <<= 1) ls += __shfl_xor(ls, o);
      wgt[t] = we;
      if (t == 0) { mlS[0] = m; mlS[1] = ls; }
    }
    __syncthreads();

    // ctx partial: coalesced global re-read of this strip (L2/L3-warm)
    {
      const float* __restrict__ ep = enc + ((size_t)b * S_ + ridxu * 64) * H_ + t;
      float a = 0.f;
#pragma unroll 8
      for (int s = 0; s < 64; ++s) a = fmaf(wgt[s], ep[(size_t)s * H_], a);
      ctxp[((size_t)ridxu * B_ + b) * H_ + t] = a;
    }
    if (t < 2) mlout[(ridxu * B_ + b) * 2 + t] = mlS[t];
    // drain: resets per-wave vm counts (washes divergent store + ctx loads)
    asm volatile("s_waitcnt vmcnt(0)" ::: "memory");
  }
#undef STAGEG
}

// ---------------- flash combine + h_new GEMV ----------------
__global__ __launch_bounds__(256) void combine_hnew(
    const float* __restrict__ ctxp, const float* __restrict__ mlout,
    const float* __restrict__ xWih, const float* __restrict__ W_hh,
    float* __restrict__ out_h, __bf16* __restrict__ hn) {
  const int b = blockIdx.x, h = threadIdx.x;
  __shared__ float cs[H_];
  float M = -3.4e38f;
#pragma unroll
  for (int cc = 0; cc < NCHK; ++cc) M = fmaxf(M, mlout[(cc * B_ + b) * 2]);
  float num = 0.f, den = 0.f;
#pragma unroll
  for (int cc = 0; cc < NCHK; ++cc) {
    const float mw = __expf(mlout[(cc * B_ + b) * 2] - M);
    den = fmaf(mw, mlout[(cc * B_ + b) * 2 + 1], den);
    num = fmaf(mw, ctxp[((size_t)cc * B_ + b) * H_ + h], num);
  }
  cs[h] = num / den;
  __syncthreads();
  const float* __restrict__ wr = W_hh + (size_t)h * H_;
  float a = xWih[b * H_ + h];
  for (int k = 0; k < H_; k += 4) {
    const float4 w4 = *reinterpret_cast<const float4*>(wr + k);
    const float4 c4 = *reinterpret_cast<const float4*>(&cs[k]);
    a = fmaf(c4.x, w4.x, a); a = fmaf(c4.y, w4.y, a);
    a = fmaf(c4.z, w4.z, a); a = fmaf(c4.w, w4.w, a);
  }
  const float hv = fast_tanh(a);
  out_h[b * H_ + h] = hv;
  hn[b * H_ + h] = (__bf16)hv;
}

// ---------------- logits = h_new @ W_out^T + b_out via pure-bf16 MFMA ----------------
__global__ __launch_bounds__(256) void logits_mfma(
    const float* __restrict__ Wout, const float* __restrict__ bout,
    const __bf16* __restrict__ hn, float* __restrict__ logits) {
  const int v0 = blockIdx.x * 64;
  const int t = threadIdx.x;
  const int wv = t >> 6, l = t & 63, l15 = l & 15, lg = l >> 4;

  __shared__ __bf16 Wsub[8][64][32];

  {
    const int srow = t >> 2, sg = t & 3;
    const int wslot = (sg + (srow >> 1)) & 3;
    const int vc = (v0 + srow) < V_ ? (v0 + srow) : (V_ - 1);
    const float* __restrict__ wr = Wout + (size_t)vc * H_ + sg * 8;
#pragma unroll
    for (int ks = 0; ks < 8; ++ks) {
      const float4 f0 = *reinterpret_cast<const float4*>(wr + ks * 32);
      const float4 f1 = *reinterpret_cast<const float4*>(wr + ks * 32 + 4);
      const float xv[8] = {f0.x, f0.y, f0.z, f0.w, f1.x, f1.y, f1.z, f1.w};
      bf16x8 h8;
#pragma unroll
      for (int j = 0; j < 8; ++j) h8[j] = (__bf16)xv[j];
      *reinterpret_cast<bf16x8*>(&Wsub[ks][srow][wslot * 8]) = h8;
    }
  }
  __syncthreads();

  f32x4 acc[4];
#pragma unroll
  for (int i = 0; i < 4; ++i) acc[i] = (f32x4)(0.f);
  const int colb = wv * 16 + l15;
#pragma unroll
  for (int k = 0; k < 8; ++k) {
    const bf16x8 bfrag = *reinterpret_cast<const bf16x8*>(hn + (size_t)colb * H_ + k * 32 + lg * 8);
    bf16x8 ah[4];
#pragma unroll
    for (int rf = 0; rf < 4; ++rf) {
      const int rr = rf * 16 + l15;
      const int slot = (lg + (rr >> 1)) & 3;
      ah[rf] = *reinterpret_cast<const bf16x8*>(&Wsub[k][rr][slot * 8]);
    }
#pragma unroll
    for (int rf = 0; rf < 4; ++rf)
      acc[rf] = mfma16(ah[rf], bfrag, acc[rf]);
  }
#pragma unroll
  for (int rf = 0; rf < 4; ++rf) {
    const int v = v0 + rf * 16 + lg * 4;
    if (v < V_) {
      const float4 bo = *reinterpret_cast<const float4*>(bout + v);
      float4 o;
      o.x = acc[rf][0] + bo.x; o.y = acc[rf][1] + bo.y;
      o.z = acc[rf][2] + bo.z; o.w = acc[rf][3] + bo.w;
      *reinterpret_cast<float4*>(logits + (size_t)colb * V_ + v) = o;
    }
  }
}

extern "C" void kernel_launch(void* const* d_in, const int* in_sizes, int n_in,
                              void* d_out, int out_size, void* d_ws, size_t ws_size,
                              hipStream_t stream) {
  const int*   inp  = (const int*)  d_in[0];
  const float* enc  = (const float*)d_in[2];
  const float* emb  = (const float*)d_in[3];
  const float* U    = (const float*)d_in[4];
  const float* W    = (const float*)d_in[5];
  const float* v    = (const float*)d_in[6];
  const float* W_ih = (const float*)d_in[7];
  const float* W_hh = (const float*)d_in[8];
  const float* b_ih = (const float*)d_in[9];
  const float* b_hh = (const float*)d_in[10];
  const float* Wout = (const float*)d_in[11];
  const float* bout = (const float*)d_in[12];

  float* logits = (float*)d_out;
  float* out_h  = logits + (size_t)B_ * V_;

  float* ws    = (float*)d_ws;
  __bf16* wt2  = (__bf16*)ws;                       // 128 KB
  float* xU    = ws + 32768;
  float* xWih  = xU + B_ * H_;
  float* ctxp  = xWih + B_ * H_;                    // NCHK*B*H
  float* mlout = ctxp + (size_t)NCHK * B_ * H_;     // NCHK*B*2
  __bf16* hn   = (__bf16*)(mlout + NCHK * B_ * 2);  // B*H bf16

  prep_k<<<dim3(B_), dim3(256), 0, stream>>>(inp, emb, U, W_ih, b_ih, b_hh, xU, xWih);
  prep_w<<<dim3(H_ * H_ / 256), dim3(256), 0, stream>>>(W, wt2);
  attn_fused<<<dim3(512), dim3(256), 0, stream>>>(enc, wt2, xU, v, ctxp, mlout);
  combine_hnew<<<dim3(B_), dim3(256), 0, stream>>>(ctxp, mlout, xWih, W_hh, out_h, hn);
  logits_mfma<<<dim3((V_ + 63) / 64), dim3(256), 0, stream>>>(Wout, bout, hn, logits);
}

// Round 23
// 97.595 us; speedup vs baseline: 1.3232x; 1.3232x over previous
//
#include <hip/hip_runtime.h>
#include <hip/hip_bf16.h>
#include <math.h>

#define V_ 50000
#define E_ 256
#define H_ 256
#define B_ 64
#define S_ 2048
#define NCHK 32            // S/64 strips == score chunks

typedef __attribute__((ext_vector_type(4))) float f32x4;
typedef __attribute__((ext_vector_type(16))) float f32x16;
typedef __attribute__((ext_vector_type(8))) __bf16 bf16x8;

static __device__ __forceinline__ f32x4 mfma16(bf16x8 a, bf16x8 b, f32x4 c) {
  return __builtin_amdgcn_mfma_f32_16x16x32_bf16(a, b, c, 0, 0, 0);
}
static __device__ __forceinline__ f32x16 mfma32(bf16x8 a, bf16x8 b, f32x16 c) {
  return __builtin_amdgcn_mfma_f32_32x32x16_bf16(a, b, c, 0, 0, 0);
}
static __device__ __forceinline__ float fast_tanh(float x) {
  const float e2 = __expf(2.0f * x);
  return 1.0f - 2.0f / (e2 + 1.0f);
}
// async global->LDS, 16B per lane; dst is wave-uniform base (HW adds lane*16)
static __device__ __forceinline__ void gll16(const float* g, void* l) {
  __builtin_amdgcn_global_load_lds(
      (const __attribute__((address_space(1))) void*)g,
      (__attribute__((address_space(3))) void*)l, 16, 0, 0);
}

// ---------------- prep: xU = x@U ; xWih = x@W_ih^T + b_ih + b_hh ----------------
__global__ __launch_bounds__(256) void prep_k(
    const int* __restrict__ inp, const float* __restrict__ emb,
    const float* __restrict__ U, const float* __restrict__ W_ih,
    const float* __restrict__ b_ih, const float* __restrict__ b_hh,
    float* __restrict__ xU, float* __restrict__ xWih) {
  const int b = blockIdx.x, h = threadIdx.x;
  __shared__ float xs[H_];
  xs[h] = emb[(size_t)inp[b] * E_ + h];
  __syncthreads();
  float au = 0.f, aw = 0.f;
  const float* __restrict__ wir = W_ih + (size_t)h * E_;
  for (int k = 0; k < H_; k += 4) {
    const float4 x4 = *reinterpret_cast<const float4*>(&xs[k]);
    const float4 w4 = *reinterpret_cast<const float4*>(wir + k);
    aw = fmaf(x4.x, w4.x, aw); aw = fmaf(x4.y, w4.y, aw);
    aw = fmaf(x4.z, w4.z, aw); aw = fmaf(x4.w, w4.w, aw);
    au = fmaf(x4.x, U[(size_t)(k + 0) * H_ + h], au);
    au = fmaf(x4.y, U[(size_t)(k + 1) * H_ + h], au);
    au = fmaf(x4.z, U[(size_t)(k + 2) * H_ + h], au);
    au = fmaf(x4.w, U[(size_t)(k + 3) * H_ + h], au);
  }
  xU[b * H_ + h] = au;
  xWih[b * H_ + h] = aw + b_ih[h] + b_hh[h];
}

// ---------------- prep W: bf16 table wt2[k>>3][col][k&7] (koct-major) ----------------
__global__ __launch_bounds__(256) void prep_w(
    const float* __restrict__ W, __bf16* __restrict__ wt2) {
  const int idx = blockIdx.x * 256 + threadIdx.x;
  const int k = idx >> 8, col = idx & 255;
  wt2[((size_t)(k >> 3) * 256 + col) * 8 + (k & 7)] = (__bf16)W[(size_t)k * H_ + col];
}

// ---------------- fused attention: 16-slot ring, DEEP prologue (14 slabs in flight) ----------------
// 256 thr (4 waves = 2 rg x 2 cg); block = 64 rows x 256 cols; wave = 32x128.
// A: 16-slot LDS ring (64 KB); slabs 0-13 staged up front, 14/15 at it0.
//    Counted vmcnt per iter (exact younger-ops counts), barrier per iter.
// ctx partial reads the staged f32 tile from LDS (no global re-read).
// A -> single bf16 convert (1-term, absmax 0.25 verified).
// B: single koct-major W table from L2, 2-deep register dbuf.
__global__ __launch_bounds__(256, 3) void attn_fused(
    const float* __restrict__ enc, const __bf16* __restrict__ wt2,
    const float* __restrict__ xU, const float* __restrict__ vv,
    float* __restrict__ ctxp, float* __restrict__ mlout) {
  const int t = threadIdx.x;
  const int w = t >> 6, l = t & 63, l31 = l & 31, h5 = l >> 5;
  const int rg = w >> 1, cg = w & 1;

  __shared__ __align__(16) char Aring[16 * 4096];   // 64 KB, one slot per slab
  __shared__ float ered[2][64];
  __shared__ float wgt[64];
  __shared__ float mlS[2];

  const int ridx = blockIdx.x;        // 64-row strip (0..31)
  const int b = blockIdx.y;
  const int s0 = ridx * 64;

  // staging map: lane i covers row i/4 (4 lanes per row, 64B), chunk i&3;
  // logical kchunk = pch ^ ((row>>1)&3)  (verified slot rotation)
  const int srow = t >> 2;
  const int pch = t & 3;
  const int kch = pch ^ ((srow >> 1) & 3);
  const float* __restrict__ encSrc = enc + ((size_t)b * S_ + s0 + srow) * H_ + kch * 4;

#define STAGE(ks_)                                                 \
  gll16(encSrc + (ks_) * 16, Aring + (ks_) * 4096 + w * 1024);     \
  __builtin_amdgcn_sched_barrier(0);

  // prologue: 14 slabs in flight + B buf 0 (both k-halves)
  STAGE(0);  STAGE(1);  STAGE(2);  STAGE(3);  STAGE(4);  STAGE(5);  STAGE(6);
  STAGE(7);  STAGE(8);  STAGE(9);  STAGE(10); STAGE(11); STAGE(12); STAGE(13);
  bf16x8 bh[2][2][4];   // [buf][half][cf]
#pragma unroll
  for (int hh = 0; hh < 2; ++hh)
#pragma unroll
    for (int cf = 0; cf < 4; ++cf) {
      const int col = cg * 128 + cf * 32 + l31;
      bh[0][hh][cf] = *reinterpret_cast<const bf16x8*>(
          wt2 + ((size_t)(hh * 2 + h5) * 256 + col) * 8);
    }
  __builtin_amdgcn_sched_barrier(0);

  f32x16 acc[4];
#pragma unroll
  for (int cf = 0; cf < 4; ++cf) acc[cf] = (f32x16)(0.f);

  const int r = rg * 32 + l31;
  const int sxor = (r >> 1) & 3;
  const char* arow = Aring + r * 64;

#pragma unroll
  for (int it = 0; it < 8; ++it) {
    // counted wait: slabs {2it, 2it+1} complete. N = exact count of vm ops
    // issued AFTER slab 2it+1's gll16 (in-order retirement => safe):
    if (it == 0)      asm volatile("s_waitcnt vmcnt(20)" ::: "memory");
    else if (it == 1) asm volatile("s_waitcnt vmcnt(28)" ::: "memory");
    else if (it == 2) asm volatile("s_waitcnt vmcnt(34)" ::: "memory");
    else if (it == 3) asm volatile("s_waitcnt vmcnt(40)" ::: "memory");
    else if (it == 4) asm volatile("s_waitcnt vmcnt(46)" ::: "memory");
    else if (it == 5) asm volatile("s_waitcnt vmcnt(52)" ::: "memory");
    else if (it == 6) asm volatile("s_waitcnt vmcnt(58)" ::: "memory");
    else              asm volatile("s_waitcnt vmcnt(56)" ::: "memory");
    __builtin_amdgcn_s_barrier();
    __builtin_amdgcn_sched_barrier(0);
    // stage final slabs 14,15 at it0 (their slots are untouched)
    if (it == 0) { STAGE(14); STAGE(15); }
    // B prefetch for iter it+1 (8 loads, L2)
    const int pb = it & 1;
    if (it < 7) {
#pragma unroll
      for (int hh = 0; hh < 2; ++hh) {
        const int koct = (2 * (it + 1) + hh) * 2 + h5;
#pragma unroll
        for (int cf = 0; cf < 4; ++cf) {
          const int col = cg * 128 + cf * 32 + l31;
          bh[pb ^ 1][hh][cf] = *reinterpret_cast<const bf16x8*>(
              wt2 + ((size_t)koct * 256 + col) * 8);
        }
      }
    }
    __builtin_amdgcn_sched_barrier(0);
    // two k-halves: ds_read + single bf16 convert + 4 mfma32 each
#pragma unroll
    for (int hh = 0; hh < 2; ++hh) {
      const int ks = 2 * it + hh;
      const char* sb = arow + ks * 4096;
      const f32x4 c0 = *reinterpret_cast<const f32x4*>(sb + (((2 * h5 + 0) ^ sxor) << 4));
      const f32x4 c1 = *reinterpret_cast<const f32x4*>(sb + (((2 * h5 + 1) ^ sxor) << 4));
      bf16x8 ab;
      {
        const float xa[8] = {c0[0], c0[1], c0[2], c0[3], c1[0], c1[1], c1[2], c1[3]};
#pragma unroll
        for (int j = 0; j < 8; ++j) ab[j] = (__bf16)xa[j];
      }
#pragma unroll
      for (int cf = 0; cf < 4; ++cf) acc[cf] = mfma32(ab, bh[pb][hh][cf], acc[cf]);
    }
  }
#undef STAGE

  // ---- epilogue: tanh + v-dot over wave's 128 cols; 32-lane reduce ----
  float xu[4], vw[4];
#pragma unroll
  for (int cf = 0; cf < 4; ++cf) {
    const int col = cg * 128 + cf * 32 + l31;
    xu[cf] = xU[b * H_ + col];
    vw[cf] = vv[col];
  }
  float rs[16];
#pragma unroll
  for (int reg = 0; reg < 16; ++reg) {
    float s = 0.f;
#pragma unroll
    for (int cf = 0; cf < 4; ++cf)
      s += fast_tanh(xu[cf] + acc[cf][reg]) * vw[cf];
    rs[reg] = s;
  }
#pragma unroll
  for (int o = 1; o < 32; o <<= 1)
#pragma unroll
    for (int reg = 0; reg < 16; ++reg)
      rs[reg] += __shfl_xor(rs[reg], o);
  if (l31 == 0) {
#pragma unroll
    for (int reg = 0; reg < 16; ++reg)
      ered[cg][rg * 32 + (reg & 3) + 8 * (reg >> 2) + 4 * h5] = rs[reg];
  }
  __syncthreads();

  // ---- softmax stats for this 64-row strip ----
  if (t < 64) {
    const float es = ered[0][t] + ered[1][t];
    float m = es;
#pragma unroll
    for (int o = 1; o < 64; o <<= 1) m = fmaxf(m, __shfl_xor(m, o));
    const float we = __expf(es - m);
    float ls = we;
#pragma unroll
    for (int o = 1; o < 64; o <<= 1) ls += __shfl_xor(ls, o);
    wgt[t] = we;
    if (t == 0) { mlS[0] = m; mlS[1] = ls; }
  }
  __syncthreads();

  // ---- ctx partial: read the staged f32 tile from LDS (no global re-read) ----
  {
    const int h = t;
    const int ks2 = h >> 4, c2 = (h >> 2) & 3, e2 = h & 3;
    const char* base = Aring + ks2 * 4096 + e2 * 4;
    float a = 0.f;
#pragma unroll 8
    for (int s = 0; s < 64; ++s) {
      const int pch2 = c2 ^ ((s >> 1) & 3);
      const float ev = *reinterpret_cast<const float*>(
          base + (s >> 4) * 1024 + (s & 15) * 64 + pch2 * 16);
      a = fmaf(wgt[s], ev, a);
    }
    ctxp[((size_t)ridx * B_ + b) * H_ + h] = a;
  }
  if (t < 2) mlout[(ridx * B_ + b) * 2 + t] = mlS[t];
}

// ---------------- flash combine + h_new GEMV ----------------
__global__ __launch_bounds__(256) void combine_hnew(
    const float* __restrict__ ctxp, const float* __restrict__ mlout,
    const float* __restrict__ xWih, const float* __restrict__ W_hh,
    float* __restrict__ out_h, __bf16* __restrict__ hn) {
  const int b = blockIdx.x, h = threadIdx.x;
  __shared__ float cs[H_];
  float M = -3.4e38f;
#pragma unroll
  for (int cc = 0; cc < NCHK; ++cc) M = fmaxf(M, mlout[(cc * B_ + b) * 2]);
  float num = 0.f, den = 0.f;
#pragma unroll
  for (int cc = 0; cc < NCHK; ++cc) {
    const float mw = __expf(mlout[(cc * B_ + b) * 2] - M);
    den = fmaf(mw, mlout[(cc * B_ + b) * 2 + 1], den);
    num = fmaf(mw, ctxp[((size_t)cc * B_ + b) * H_ + h], num);
  }
  cs[h] = num / den;
  __syncthreads();
  const float* __restrict__ wr = W_hh + (size_t)h * H_;
  float a = xWih[b * H_ + h];
  for (int k = 0; k < H_; k += 4) {
    const float4 w4 = *reinterpret_cast<const float4*>(wr + k);
    const float4 c4 = *reinterpret_cast<const float4*>(&cs[k]);
    a = fmaf(c4.x, w4.x, a); a = fmaf(c4.y, w4.y, a);
    a = fmaf(c4.z, w4.z, a); a = fmaf(c4.w, w4.w, a);
  }
  const float hv = fast_tanh(a);
  out_h[b * H_ + h] = hv;
  hn[b * H_ + h] = (__bf16)hv;
}

// ---------------- logits = h_new @ W_out^T + b_out via pure-bf16 MFMA ----------------
__global__ __launch_bounds__(256) void logits_mfma(
    const float* __restrict__ Wout, const float* __restrict__ bout,
    const __bf16* __restrict__ hn, float* __restrict__ logits) {
  const int v0 = blockIdx.x * 64;
  const int t = threadIdx.x;
  const int wv = t >> 6, l = t & 63, l15 = l & 15, lg = l >> 4;

  __shared__ __bf16 Wsub[8][64][32];

  {
    const int srow = t >> 2, sg = t & 3;
    const int wslot = (sg + (srow >> 1)) & 3;
    const int vc = (v0 + srow) < V_ ? (v0 + srow) : (V_ - 1);
    const float* __restrict__ wr = Wout + (size_t)vc * H_ + sg * 8;
#pragma unroll
    for (int ks = 0; ks < 8; ++ks) {
      const float4 f0 = *reinterpret_cast<const float4*>(wr + ks * 32);
      const float4 f1 = *reinterpret_cast<const float4*>(wr + ks * 32 + 4);
      const float xv[8] = {f0.x, f0.y, f0.z, f0.w, f1.x, f1.y, f1.z, f1.w};
      bf16x8 h8;
#pragma unroll
      for (int j = 0; j < 8; ++j) h8[j] = (__bf16)xv[j];
      *reinterpret_cast<bf16x8*>(&Wsub[ks][srow][wslot * 8]) = h8;
    }
  }
  __syncthreads();

  f32x4 acc[4];
#pragma unroll
  for (int i = 0; i < 4; ++i) acc[i] = (f32x4)(0.f);
  const int colb = wv * 16 + l15;
#pragma unroll
  for (int k = 0; k < 8; ++k) {
    const bf16x8 bfrag = *reinterpret_cast<const bf16x8*>(hn + (size_t)colb * H_ + k * 32 + lg * 8);
    bf16x8 ah[4];
#pragma unroll
    for (int rf = 0; rf < 4; ++rf) {
      const int rr = rf * 16 + l15;
      const int slot = (lg + (rr >> 1)) & 3;
      ah[rf] = *reinterpret_cast<const bf16x8*>(&Wsub[k][rr][slot * 8]);
    }
#pragma unroll
    for (int rf = 0; rf < 4; ++rf)
      acc[rf] = mfma16(ah[rf], bfrag, acc[rf]);
  }
#pragma unroll
  for (int rf = 0; rf < 4; ++rf) {
    const int v = v0 + rf * 16 + lg * 4;
    if (v < V_) {
      const float4 bo = *reinterpret_cast<const float4*>(bout + v);
      float4 o;
      o.x = acc[rf][0] + bo.x; o.y = acc[rf][1] + bo.y;
      o.z = acc[rf][2] + bo.z; o.w = acc[rf][3] + bo.w;
      *reinterpret_cast<float4*>(logits + (size_t)colb * V_ + v) = o;
    }
  }
}

extern "C" void kernel_launch(void* const* d_in, const int* in_sizes, int n_in,
                              void* d_out, int out_size, void* d_ws, size_t ws_size,
                              hipStream_t stream) {
  const int*   inp  = (const int*)  d_in[0];
  const float* enc  = (const float*)d_in[2];
  const float* emb  = (const float*)d_in[3];
  const float* U    = (const float*)d_in[4];
  const float* W    = (const float*)d_in[5];
  const float* v    = (const float*)d_in[6];
  const float* W_ih = (const float*)d_in[7];
  const float* W_hh = (const float*)d_in[8];
  const float* b_ih = (const float*)d_in[9];
  const float* b_hh = (const float*)d_in[10];
  const float* Wout = (const float*)d_in[11];
  const float* bout = (const float*)d_in[12];

  float* logits = (float*)d_out;
  float* out_h  = logits + (size_t)B_ * V_;

  float* ws    = (float*)d_ws;
  __bf16* wt2  = (__bf16*)ws;                       // 128 KB
  float* xU    = ws + 32768;
  float* xWih  = xU + B_ * H_;
  float* ctxp  = xWih + B_ * H_;                    // NCHK*B*H
  float* mlout = ctxp + (size_t)NCHK * B_ * H_;     // NCHK*B*2
  __bf16* hn   = (__bf16*)(mlout + NCHK * B_ * 2);  // B*H bf16

  prep_k<<<dim3(B_), dim3(256), 0, stream>>>(inp, emb, U, W_ih, b_ih, b_hh, xU, xWih);
  prep_w<<<dim3(H_ * H_ / 256), dim3(256), 0, stream>>>(W, wt2);
  attn_fused<<<dim3(NCHK, B_), dim3(256), 0, stream>>>(enc, wt2, xU, v, ctxp, mlout);
  combine_hnew<<<dim3(B_), dim3(256), 0, stream>>>(ctxp, mlout, xWih, W_hh, out_h, hn);
  logits_mfma<<<dim3((V_ + 63) / 64), dim3(256), 0, stream>>>(Wout, bout, hn, logits);
}

// Round 24
// 95.926 us; speedup vs baseline: 1.3462x; 1.0174x over previous
//
#include <hip/hip_runtime.h>
#include <hip/hip_bf16.h>
#include <math.h>

#define V_ 50000
#define E_ 256
#define H_ 256
#define B_ 64
#define S_ 2048
#define NCHK 32            // S/64 strips == score chunks

typedef __attribute__((ext_vector_type(4))) float f32x4;
typedef __attribute__((ext_vector_type(16))) float f32x16;
typedef __attribute__((ext_vector_type(8))) __bf16 bf16x8;

static __device__ __forceinline__ f32x4 mfma16(bf16x8 a, bf16x8 b, f32x4 c) {
  return __builtin_amdgcn_mfma_f32_16x16x32_bf16(a, b, c, 0, 0, 0);
}
static __device__ __forceinline__ f32x16 mfma32(bf16x8 a, bf16x8 b, f32x16 c) {
  return __builtin_amdgcn_mfma_f32_32x32x16_bf16(a, b, c, 0, 0, 0);
}
static __device__ __forceinline__ float fast_tanh(float x) {
  const float e2 = __expf(2.0f * x);
  return 1.0f - 2.0f / (e2 + 1.0f);
}
// async global->LDS, 16B per lane; dst is wave-uniform base (HW adds lane*16)
static __device__ __forceinline__ void gll16(const float* g, void* l) {
  __builtin_amdgcn_global_load_lds(
      (const __attribute__((address_space(1))) void*)g,
      (__attribute__((address_space(3))) void*)l, 16, 0, 0);
}

// ---------------- fused prep: blocks 0..63 -> xU/xWih ; blocks 64..319 -> W table ----------------
__global__ __launch_bounds__(256) void prep_fused(
    const int* __restrict__ inp, const float* __restrict__ emb,
    const float* __restrict__ U, const float* __restrict__ W_ih,
    const float* __restrict__ b_ih, const float* __restrict__ b_hh,
    const float* __restrict__ W, float* __restrict__ xU,
    float* __restrict__ xWih, __bf16* __restrict__ wt2) {
  if (blockIdx.x < 64) {
    const int b = blockIdx.x, h = threadIdx.x;
    __shared__ float xs[H_];
    xs[h] = emb[(size_t)inp[b] * E_ + h];
    __syncthreads();
    float au = 0.f, aw = 0.f;
    const float* __restrict__ wir = W_ih + (size_t)h * E_;
    for (int k = 0; k < H_; k += 4) {
      const float4 x4 = *reinterpret_cast<const float4*>(&xs[k]);
      const float4 w4 = *reinterpret_cast<const float4*>(wir + k);
      aw = fmaf(x4.x, w4.x, aw); aw = fmaf(x4.y, w4.y, aw);
      aw = fmaf(x4.z, w4.z, aw); aw = fmaf(x4.w, w4.w, aw);
      au = fmaf(x4.x, U[(size_t)(k + 0) * H_ + h], au);
      au = fmaf(x4.y, U[(size_t)(k + 1) * H_ + h], au);
      au = fmaf(x4.z, U[(size_t)(k + 2) * H_ + h], au);
      au = fmaf(x4.w, U[(size_t)(k + 3) * H_ + h], au);
    }
    xU[b * H_ + h] = au;
    xWih[b * H_ + h] = aw + b_ih[h] + b_hh[h];
  } else {
    const int idx = (blockIdx.x - 64) * 256 + threadIdx.x;
    const int k = idx >> 8, col = idx & 255;
    wt2[((size_t)(k >> 3) * 256 + col) * 8 + (k & 7)] = (__bf16)W[(size_t)k * H_ + col];
  }
}

// ---------------- fused attention: R18 configuration (best attn measured: 78.5 us) ----------------
// 256 thr (4 waves = 2 rg x 2 cg); block = 64 rows x 256 cols; wave = 32x128.
// A: 8-slot shared LDS ring (32 KB), slabs via global_load_lds, 6 in flight,
//    ONE barrier + counted vmcnt per 2 slabs (8 iters). A -> single bf16 convert.
// B: single koct-major W table from L2, 2-deep register dbuf.
// ctx partial: coalesced global re-read (L2/L3-warm).
__global__ __launch_bounds__(256, 3) void attn_fused(
    const float* __restrict__ enc, const __bf16* __restrict__ wt2,
    const float* __restrict__ xU, const float* __restrict__ vv,
    float* __restrict__ ctxp, float* __restrict__ mlout) {
  const int t = threadIdx.x;
  const int w = t >> 6, l = t & 63, l31 = l & 31, h5 = l >> 5;
  const int rg = w >> 1, cg = w & 1;

  __shared__ __align__(16) char Aring[8 * 4096];   // 32 KB
  __shared__ float ered[2][64];
  __shared__ float wgt[64];
  __shared__ float mlS[2];

  const int ridx = blockIdx.x;        // 64-row strip (0..31)
  const int b = blockIdx.y;
  const int s0 = ridx * 64;

  // staging map: lane i covers row i/4 (4 lanes per row, 64B), chunk i&3;
  // logical kchunk = pch ^ ((row>>1)&3)  (verified slot rotation)
  const int srow = t >> 2;
  const int pch = t & 3;
  const int kch = pch ^ ((srow >> 1) & 3);
  const float* __restrict__ encSrc = enc + ((size_t)b * S_ + s0 + srow) * H_ + kch * 4;

#define STAGE(ks_)                                                   \
  gll16(encSrc + (ks_) * 16, Aring + ((ks_) & 7) * 4096 + w * 1024); \
  __builtin_amdgcn_sched_barrier(0);

  // prologue: 6 slabs in flight + B buf 0 (both k-halves)
  STAGE(0); STAGE(1); STAGE(2); STAGE(3); STAGE(4); STAGE(5);
  bf16x8 bh[2][2][4];   // [buf][half][cf]
#pragma unroll
  for (int hh = 0; hh < 2; ++hh)
#pragma unroll
    for (int cf = 0; cf < 4; ++cf) {
      const int col = cg * 128 + cf * 32 + l31;
      bh[0][hh][cf] = *reinterpret_cast<const bf16x8*>(
          wt2 + ((size_t)(hh * 2 + h5) * 256 + col) * 8);
    }
  __builtin_amdgcn_sched_barrier(0);

  f32x16 acc[4];
#pragma unroll
  for (int cf = 0; cf < 4; ++cf) acc[cf] = (f32x16)(0.f);

  const int r = rg * 32 + l31;
  const int sxor = (r >> 1) & 3;
  const char* arow = Aring + r * 64;

#pragma unroll
  for (int it = 0; it < 8; ++it) {
    // counted wait: slabs {2it, 2it+1} complete (ops issued after slab 2it+1):
    // it0: s2..s5(4)+B0(8)=12 ; it1: s4,s5(2)+B0+i0(10)=20 ; it2..5: 28 ;
    // it6: B4(8)+i4(10)+B6(8)=26 ; it7: B5(8)+B6(8)+B7(8)=24
    if (it == 0)      asm volatile("s_waitcnt vmcnt(12)" ::: "memory");
    else if (it == 1) asm volatile("s_waitcnt vmcnt(20)" ::: "memory");
    else if (it <= 5) asm volatile("s_waitcnt vmcnt(28)" ::: "memory");
    else if (it == 6) asm volatile("s_waitcnt vmcnt(26)" ::: "memory");
    else              asm volatile("s_waitcnt vmcnt(24)" ::: "memory");
    __builtin_amdgcn_s_barrier();
    __builtin_amdgcn_sched_barrier(0);
    // stage slabs 2it+6, 2it+7 (slots free: read finished 2 iters ago)
    if (it <= 4) { STAGE(2 * it + 6); STAGE(2 * it + 7); }
    // B prefetch for iter it+1 (8 loads, L2)
    const int pb = it & 1;
    if (it < 7) {
#pragma unroll
      for (int hh = 0; hh < 2; ++hh) {
        const int koct = (2 * (it + 1) + hh) * 2 + h5;
#pragma unroll
        for (int cf = 0; cf < 4; ++cf) {
          const int col = cg * 128 + cf * 32 + l31;
          bh[pb ^ 1][hh][cf] = *reinterpret_cast<const bf16x8*>(
              wt2 + ((size_t)koct * 256 + col) * 8);
        }
      }
    }
    __builtin_amdgcn_sched_barrier(0);
    // two k-halves: ds_read + single bf16 convert + 4 mfma32 each
#pragma unroll
    for (int hh = 0; hh < 2; ++hh) {
      const int ks = 2 * it + hh;
      const char* sb = arow + (ks & 7) * 4096;
      const f32x4 c0 = *reinterpret_cast<const f32x4*>(sb + (((2 * h5 + 0) ^ sxor) << 4));
      const f32x4 c1 = *reinterpret_cast<const f32x4*>(sb + (((2 * h5 + 1) ^ sxor) << 4));
      bf16x8 ab;
      {
        const float xa[8] = {c0[0], c0[1], c0[2], c0[3], c1[0], c1[1], c1[2], c1[3]};
#pragma unroll
        for (int j = 0; j < 8; ++j) ab[j] = (__bf16)xa[j];
      }
#pragma unroll
      for (int cf = 0; cf < 4; ++cf) acc[cf] = mfma32(ab, bh[pb][hh][cf], acc[cf]);
    }
  }
#undef STAGE

  // ---- epilogue: tanh + v-dot over wave's 128 cols; 32-lane reduce ----
  float xu[4], vw[4];
#pragma unroll
  for (int cf = 0; cf < 4; ++cf) {
    const int col = cg * 128 + cf * 32 + l31;
    xu[cf] = xU[b * H_ + col];
    vw[cf] = vv[col];
  }
  float rs[16];
#pragma unroll
  for (int reg = 0; reg < 16; ++reg) {
    float s = 0.f;
#pragma unroll
    for (int cf = 0; cf < 4; ++cf)
      s += fast_tanh(xu[cf] + acc[cf][reg]) * vw[cf];
    rs[reg] = s;
  }
#pragma unroll
  for (int o = 1; o < 32; o <<= 1)
#pragma unroll
    for (int reg = 0; reg < 16; ++reg)
      rs[reg] += __shfl_xor(rs[reg], o);
  if (l31 == 0) {
#pragma unroll
    for (int reg = 0; reg < 16; ++reg)
      ered[cg][rg * 32 + (reg & 3) + 8 * (reg >> 2) + 4 * h5] = rs[reg];
  }
  __syncthreads();

  // ---- softmax stats for this 64-row strip ----
  if (t < 64) {
    const float es = ered[0][t] + ered[1][t];
    float m = es;
#pragma unroll
    for (int o = 1; o < 64; o <<= 1) m = fmaxf(m, __shfl_xor(m, o));
    const float we = __expf(es - m);
    float ls = we;
#pragma unroll
    for (int o = 1; o < 64; o <<= 1) ls += __shfl_xor(ls, o);
    wgt[t] = we;
    if (t == 0) { mlS[0] = m; mlS[1] = ls; }
  }
  __syncthreads();

  // ---- ctx partial for this strip: coalesced re-read (L2/L3-warm) ----
  {
    const float* __restrict__ ep = enc + ((size_t)b * S_ + s0) * H_ + t;
    float a = 0.f;
#pragma unroll 8
    for (int s = 0; s < 64; ++s) a = fmaf(wgt[s], ep[(size_t)s * H_], a);
    ctxp[((size_t)ridx * B_ + b) * H_ + t] = a;
  }
  if (t < 2) mlout[(ridx * B_ + b) * 2 + t] = mlS[t];
}

// ---------------- flash combine + h_new GEMV ----------------
__global__ __launch_bounds__(256) void combine_hnew(
    const float* __restrict__ ctxp, const float* __restrict__ mlout,
    const float* __restrict__ xWih, const float* __restrict__ W_hh,
    float* __restrict__ out_h, __bf16* __restrict__ hn) {
  const int b = blockIdx.x, h = threadIdx.x;
  __shared__ float cs[H_];
  float M = -3.4e38f;
#pragma unroll
  for (int cc = 0; cc < NCHK; ++cc) M = fmaxf(M, mlout[(cc * B_ + b) * 2]);
  float num = 0.f, den = 0.f;
#pragma unroll
  for (int cc = 0; cc < NCHK; ++cc) {
    const float mw = __expf(mlout[(cc * B_ + b) * 2] - M);
    den = fmaf(mw, mlout[(cc * B_ + b) * 2 + 1], den);
    num = fmaf(mw, ctxp[((size_t)cc * B_ + b) * H_ + h], num);
  }
  cs[h] = num / den;
  __syncthreads();
  const float* __restrict__ wr = W_hh + (size_t)h * H_;
  float a = xWih[b * H_ + h];
  for (int k = 0; k < H_; k += 4) {
    const float4 w4 = *reinterpret_cast<const float4*>(wr + k);
    const float4 c4 = *reinterpret_cast<const float4*>(&cs[k]);
    a = fmaf(c4.x, w4.x, a); a = fmaf(c4.y, w4.y, a);
    a = fmaf(c4.z, w4.z, a); a = fmaf(c4.w, w4.w, a);
  }
  const float hv = fast_tanh(a);
  out_h[b * H_ + h] = hv;
  hn[b * H_ + h] = (__bf16)hv;
}

// ---------------- logits = h_new @ W_out^T + b_out via pure-bf16 MFMA ----------------
__global__ __launch_bounds__(256) void logits_mfma(
    const float* __restrict__ Wout, const float* __restrict__ bout,
    const __bf16* __restrict__ hn, float* __restrict__ logits) {
  const int v0 = blockIdx.x * 64;
  const int t = threadIdx.x;
  const int wv = t >> 6, l = t & 63, l15 = l & 15, lg = l >> 4;

  __shared__ __bf16 Wsub[8][64][32];

  {
    const int srow = t >> 2, sg = t & 3;
    const int wslot = (sg + (srow >> 1)) & 3;
    const int vc = (v0 + srow) < V_ ? (v0 + srow) : (V_ - 1);
    const float* __restrict__ wr = Wout + (size_t)vc * H_ + sg * 8;
#pragma unroll
    for (int ks = 0; ks < 8; ++ks) {
      const float4 f0 = *reinterpret_cast<const float4*>(wr + ks * 32);
      const float4 f1 = *reinterpret_cast<const float4*>(wr + ks * 32 + 4);
      const float xv[8] = {f0.x, f0.y, f0.z, f0.w, f1.x, f1.y, f1.z, f1.w};
      bf16x8 h8;
#pragma unroll
      for (int j = 0; j < 8; ++j) h8[j] = (__bf16)xv[j];
      *reinterpret_cast<bf16x8*>(&Wsub[ks][srow][wslot * 8]) = h8;
    }
  }
  __syncthreads();

  f32x4 acc[4];
#pragma unroll
  for (int i = 0; i < 4; ++i) acc[i] = (f32x4)(0.f);
  const int colb = wv * 16 + l15;
#pragma unroll
  for (int k = 0; k < 8; ++k) {
    const bf16x8 bfrag = *reinterpret_cast<const bf16x8*>(hn + (size_t)colb * H_ + k * 32 + lg * 8);
    bf16x8 ah[4];
#pragma unroll
    for (int rf = 0; rf < 4; ++rf) {
      const int rr = rf * 16 + l15;
      const int slot = (lg + (rr >> 1)) & 3;
      ah[rf] = *reinterpret_cast<const bf16x8*>(&Wsub[k][rr][slot * 8]);
    }
#pragma unroll
    for (int rf = 0; rf < 4; ++rf)
      acc[rf] = mfma16(ah[rf], bfrag, acc[rf]);
  }
#pragma unroll
  for (int rf = 0; rf < 4; ++rf) {
    const int v = v0 + rf * 16 + lg * 4;
    if (v < V_) {
      const float4 bo = *reinterpret_cast<const float4*>(bout + v);
      float4 o;
      o.x = acc[rf][0] + bo.x; o.y = acc[rf][1] + bo.y;
      o.z = acc[rf][2] + bo.z; o.w = acc[rf][3] + bo.w;
      *reinterpret_cast<float4*>(logits + (size_t)colb * V_ + v) = o;
    }
  }
}

extern "C" void kernel_launch(void* const* d_in, const int* in_sizes, int n_in,
                              void* d_out, int out_size, void* d_ws, size_t ws_size,
                              hipStream_t stream) {
  const int*   inp  = (const int*)  d_in[0];
  const float* enc  = (const float*)d_in[2];
  const float* emb  = (const float*)d_in[3];
  const float* U    = (const float*)d_in[4];
  const float* W    = (const float*)d_in[5];
  const float* v    = (const float*)d_in[6];
  const float* W_ih = (const float*)d_in[7];
  const float* W_hh = (const float*)d_in[8];
  const float* b_ih = (const float*)d_in[9];
  const float* b_hh = (const float*)d_in[10];
  const float* Wout = (const float*)d_in[11];
  const float* bout = (const float*)d_in[12];

  float* logits = (float*)d_out;
  float* out_h  = logits + (size_t)B_ * V_;

  float* ws    = (float*)d_ws;
  __bf16* wt2  = (__bf16*)ws;                       // 128 KB
  float* xU    = ws + 32768;
  float* xWih  = xU + B_ * H_;
  float* ctxp  = xWih + B_ * H_;                    // NCHK*B*H
  float* mlout = ctxp + (size_t)NCHK * B_ * H_;     // NCHK*B*2
  __bf16* hn   = (__bf16*)(mlout + NCHK * B_ * 2);  // B*H bf16

  prep_fused<<<dim3(64 + H_ * H_ / 256), dim3(256), 0, stream>>>(
      inp, emb, U, W_ih, b_ih, b_hh, W, xU, xWih, wt2);
  attn_fused<<<dim3(NCHK, B_), dim3(256), 0, stream>>>(enc, wt2, xU, v, ctxp, mlout);
  combine_hnew<<<dim3(B_), dim3(256), 0, stream>>>(ctxp, mlout, xWih, W_hh, out_h, hn);
  logits_mfma<<<dim3((V_ + 63) / 64), dim3(256), 0, stream>>>(Wout, bout, hn, logits);
}